// Round 6
// baseline (19903.546 us; speedup 1.0000x reference)
//
#include <hip/hip_runtime.h>
#include <hip/hip_cooperative_groups.h>
#include <math.h>

namespace cg = cooperative_groups;

typedef unsigned short u16;
typedef __attribute__((ext_vector_type(8))) short bf16x8;
typedef __attribute__((ext_vector_type(4))) float f32x4;

#define MFMA(a, b, c) __builtin_amdgcn_mfma_f32_16x16x32_bf16(a, b, c, 0, 0, 0)

#define Bsz 512
#define Tsz 128
#define Dsz 256
#define Lsz 3
#define CSs 10
#define Hsz 384
#define Gsz 1542
#define HSz 64
#define Gp  1568
#define BG  (Bsz * Gp)
#define KTH 12
#define KTX 8
#define KTC 120

// ---------------- ws layout (byte offsets) ----------------
constexpr size_t SZ_HPK = 32ull * 12 * 2 * 1024;               // 786432
constexpr size_t O_HPK  = 0;                                   // h packed hi/lo
constexpr size_t O_TPK  = O_HPK + SZ_HPK;                      // thm packed hi/lo
constexpr size_t O_CF   = O_TPK + SZ_HPK;                      // f32 B*H
constexpr size_t O_BUFH = O_CF + 786432;                       // u16 10*B*H
constexpr size_t O_BUFD = O_BUFH + 3932160;                    // f32 10*B
constexpr size_t ZERO_END = O_BUFD + 20480;                    // 6,311,936
constexpr size_t O_WPK  = ZERO_END;                            // 98*12*2*1024
constexpr size_t O_XWPK = O_WPK + 2408448;                     // 98*8*2*1024
constexpr size_t O_CPK  = O_XWPK + 1605632;                    // 24*120*1024
constexpr size_t O_SPK  = O_CPK + 2949120;                     // 4*12*2*1024
constexpr size_t O_RPK  = O_SPK + 98304;                       // 24*2*2*1024
constexpr size_t O_BC   = O_RPK + 98304;                       // f32 1568
constexpr size_t O_WT   = O_BC + 6272;
constexpr size_t O_XWP  = O_WT + 6272;                         // f32 4*B*Gp (2 buf x 2 kz)
constexpr size_t O_HWP  = O_XWP + 4ull * BG * 4;               // f32 2*B*Gp (2 kz)
constexpr size_t O_CP   = O_HWP + 2ull * BG * 4;               // f32 8*B*H
constexpr size_t O_APK  = O_CP + 8ull * Bsz * Hsz * 4;         // u16 32*120*1024B
constexpr size_t O_THO  = O_APK + 3932160;                     // f32 B*H (theme out)
constexpr size_t O_HF   = O_THO + 786432;                      // f32 B*H
constexpr size_t O_XPK  = O_HF + 786432;                       // u16 128*512KB = 67MB

__device__ __forceinline__ u16 f2bf(float f) {
    unsigned u = __float_as_uint(f);
    unsigned r = (u + 0x7FFFu + ((u >> 16) & 1u)) >> 16;
    return (u16)r;
}
__device__ __forceinline__ float bf2f(u16 v) {
    return __uint_as_float(((unsigned)v) << 16);
}
__device__ __forceinline__ float sigm(float v) { return 1.f / (1.f + expf(-v)); }

__global__ __launch_bounds__(256) void zero4(float4* __restrict__ p, int n4) {
    int i = blockIdx.x * 256 + threadIdx.x;
    if (i < n4) p[i] = make_float4(0.f, 0.f, 0.f, 0.f);
}

__global__ __launch_bounds__(256) void build_w(const float* __restrict__ kW,
                                               const float* __restrict__ kb,
                                               const float* __restrict__ rW,
                                               const float* __restrict__ rb,
                                               const float* __restrict__ sW,
                                               const float* __restrict__ rsW,
                                               u16* __restrict__ wpk,
                                               u16* __restrict__ xwpk,
                                               u16* __restrict__ spk,
                                               u16* __restrict__ rpk,
                                               float* __restrict__ bc,
                                               float* __restrict__ wt) {
    const int N1 = Gp * 384, N2 = Gp * 256, N3 = 64 * 384, N4 = 384 * 64;
    int idx = blockIdx.x * 256 + threadIdx.x;
    if (idx < N1) {
        int g = idx / 384, k = idx % 384;
        float v = (g < Gsz) ? rW[g * (Hsz + 1) + k] : 0.f;
        u16 hi = f2bf(v), lo = f2bf(v - bf2f(hi));
        size_t fo = ((size_t)((g >> 4) * KTH + (k >> 5)) * 2) * 512;
        int pos = ((g & 15) | (((k >> 3) & 3) << 4)) * 8 + (k & 7);
        wpk[fo + pos] = hi; wpk[fo + 512 + pos] = lo;
    } else if (idx < N1 + N2) {
        int i = idx - N1;
        int g = i / 256, k = i % 256;
        float v = (g < Gsz) ? kW[g * (Dsz + 1) + k] : 0.f;
        u16 hi = f2bf(v), lo = f2bf(v - bf2f(hi));
        size_t fo = ((size_t)((g >> 4) * KTX + (k >> 5)) * 2) * 512;
        int pos = ((g & 15) | (((k >> 3) & 3) << 4)) * 8 + (k & 7);
        xwpk[fo + pos] = hi; xwpk[fo + 512 + pos] = lo;
    } else if (idx < N1 + N2 + N3) {
        int i = idx - N1 - N2;
        int g = i / 384, k = i % 384;              // g<64
        float v = sW[g * Hsz + k];
        u16 hi = f2bf(v), lo = f2bf(v - bf2f(hi));
        size_t fo = ((size_t)((g >> 4) * KTH + (k >> 5)) * 2) * 512;
        int pos = ((g & 15) | (((k >> 3) & 3) << 4)) * 8 + (k & 7);
        spk[fo + pos] = hi; spk[fo + 512 + pos] = lo;
    } else if (idx < N1 + N2 + N3 + N4) {
        int i = idx - N1 - N2 - N3;
        int g = i / 64, k = i % 64;                // g<384
        float v = rsW[g * HSz + k];
        u16 hi = f2bf(v), lo = f2bf(v - bf2f(hi));
        size_t fo = ((size_t)((g >> 4) * 2 + (k >> 5)) * 2) * 512;
        int pos = ((g & 15) | (((k >> 3) & 3) << 4)) * 8 + (k & 7);
        rpk[fo + pos] = hi; rpk[fo + 512 + pos] = lo;
    } else if (idx < N1 + N2 + N3 + N4 + Gsz) {
        int g = idx - N1 - N2 - N3 - N4;
        bc[g] = kb[g] + rb[g];
        wt[g] = kW[g * (Dsz + 1) + Dsz] + rW[g * (Hsz + 1) + Hsz];
    }
}

__global__ __launch_bounds__(256) void pack_x(const float* __restrict__ x,
                                              u16* __restrict__ xpk) {
    int idx = blockIdx.x * 256 + threadIdx.x;
    int k = idx & 255, b = (idx >> 8) & 511, t = idx >> 17;
    float v = x[((size_t)b * Tsz + t) * Dsz + k];
    u16 hi = f2bf(v), lo = f2bf(v - bf2f(hi));
    size_t fo = (((size_t)t * 32 + (b >> 4)) * KTX + (k >> 5)) * 2 * 512;
    int pos = ((b & 15) | (((k >> 3) & 3) << 4)) * 8 + (k & 7);
    xpk[fo + pos] = hi;
    xpk[fo + 512 + pos] = lo;
}

__global__ __launch_bounds__(256) void pack_cw(const float* __restrict__ cW,
                                               u16* __restrict__ cpk) {
    int idx = blockIdx.x * 256 + threadIdx.x;
    if (idx >= Hsz * Hsz * CSs) return;
    int o = idx / (Hsz * CSs), k = idx % (Hsz * CSs);
    size_t fo = ((size_t)(o >> 4) * KTC + (k >> 5)) * 512;
    int pos = ((o & 15) | (((k >> 3) & 3) << 4)) * 8 + (k & 7);
    cpk[fo + pos] = f2bf(cW[idx]);
}

// split-bf16 GEMM slab: 32 rows x 112 cols per wave, kt in [k0,k1)
__device__ __forceinline__ void gemm_hx(const u16* __restrict__ A,
                                        const u16* __restrict__ B,
                                        int nkt, int k0, int k1,
                                        int mt0, int nt0, float* __restrict__ dst,
                                        int lane, int l15, int lk) {
    f32x4 acc[2][7] = {};
    for (int kt = k0; kt < k1; ++kt) {
        bf16x8 ah[2], al[2];
        #pragma unroll
        for (int mi = 0; mi < 2; ++mi) {
            size_t fb = ((size_t)((mt0 + mi) * nkt + kt) * 2) * 512 + lane * 8;
            ah[mi] = *(const bf16x8*)(A + fb);
            al[mi] = *(const bf16x8*)(A + fb + 512);
        }
        #pragma unroll
        for (int ni = 0; ni < 7; ++ni) {
            size_t fb = ((size_t)((nt0 + ni) * nkt + kt) * 2) * 512 + lane * 8;
            bf16x8 bh = *(const bf16x8*)(B + fb);
            bf16x8 bl = *(const bf16x8*)(B + fb + 512);
            #pragma unroll
            for (int mi = 0; mi < 2; ++mi) {
                acc[mi][ni] = MFMA(ah[mi], bh, acc[mi][ni]);
                acc[mi][ni] = MFMA(ah[mi], bl, acc[mi][ni]);
                acc[mi][ni] = MFMA(al[mi], bh, acc[mi][ni]);
            }
        }
    }
    #pragma unroll
    for (int mi = 0; mi < 2; ++mi)
    #pragma unroll
    for (int ni = 0; ni < 7; ++ni) {
        int col = (nt0 + ni) * 16 + l15;
        #pragma unroll
        for (int j = 0; j < 4; ++j) {
            int row = (mt0 + mi) * 16 + lk * 4 + j;
            dst[(size_t)row * Gp + col] = acc[mi][ni][j];
        }
    }
}

__global__ __launch_bounds__(512, 2) void persist(const float* __restrict__ tme,
                                                  const float* __restrict__ sb,
                                                  const float* __restrict__ rsb,
                                                  const float* __restrict__ cb,
                                                  char* __restrict__ ws,
                                                  float* __restrict__ out) {
    cg::grid_group grid = cg::this_grid();

    u16*   hpk  = (u16*)(ws + O_HPK);
    u16*   tpk  = (u16*)(ws + O_TPK);
    float* cf   = (float*)(ws + O_CF);
    u16*   bufh = (u16*)(ws + O_BUFH);
    float* bufd = (float*)(ws + O_BUFD);
    const u16* wpk  = (const u16*)(ws + O_WPK);
    const u16* xwpk = (const u16*)(ws + O_XWPK);
    const u16* cpk  = (const u16*)(ws + O_CPK);
    const u16* spk  = (const u16*)(ws + O_SPK);
    const u16* rpk  = (const u16*)(ws + O_RPK);
    const float* bc = (const float*)(ws + O_BC);
    const float* wt = (const float*)(ws + O_WT);
    float* xwp = (float*)(ws + O_XWP);
    float* hwp = (float*)(ws + O_HWP);
    float* cp  = (float*)(ws + O_CP);
    u16*   apk = (u16*)(ws + O_APK);
    float* tho = (float*)(ws + O_THO);
    float* hf  = (float*)(ws + O_HF);
    const u16* xpk = (const u16*)(ws + O_XPK);

    float* out_last = out;
    float* out_seq  = out + (size_t)Bsz * Hsz;
    float* out_dist = out_seq + (size_t)Bsz * Tsz * Hsz;

    int blk = blockIdx.x, tid = threadIdx.x;
    int wave = tid >> 6, lane = tid & 63, l15 = lane & 15, lk = lane >> 4;

    __shared__ float th1s[128][65];
    __shared__ float s_hn[Hsz];
    __shared__ float s_ld[CSs];
    __shared__ float s_fm[4], s_im[4];
    __shared__ float s_cd;

    for (int t = 0; t <= Tsz; ++t) {
        // ================= phase 1: GEMMs =================
        if (blk < 56) {                      // HW(t) = h(t-1) @ rW^T, kz-split
            if (t < Tsz) {
                int kz = blk & 1, sub = blk >> 1;
                int u = sub * 8 + wave;
                gemm_hx(hpk, wpk, KTH, kz * 6, kz * 6 + 6,
                        (u & 15) * 2, (u >> 4) * 7, hwp + (size_t)kz * BG,
                        lane, l15, lk);
            }
        } else if (blk < 112) {              // XW(t+1) = x(t+1) @ kW^T, kz-split
            if (t + 1 < Tsz) {
                int bb = blk - 56;
                int kz = bb & 1, sub = bb >> 1;
                int u = sub * 8 + wave;
                const u16* xs = xpk + (size_t)(t + 1) * 262144;
                gemm_hx(xs, xwpk, KTX, kz * 4, kz * 4 + 4,
                        (u & 15) * 2, (u >> 4) * 7,
                        xwp + (size_t)(((t + 1) & 1) * 2 + kz) * BG,
                        lane, l15, lk);
            }
        } else if (blk < 176) {              // CONV(t-1)  (t==0: bootstrap XW(0))
            if (t == 0) {
                if (blk < 168) {
                    int bb = blk - 112;
                    int kz = bb & 1, sub = bb >> 1;
                    int u = sub * 8 + wave;
                    gemm_hx(xpk, xwpk, KTX, kz * 4, kz * 4 + 4,
                            (u & 15) * 2, (u >> 4) * 7, xwp + (size_t)kz * BG,
                            lane, l15, lk);
                }
            } else {
                int u = (blk - 112) * 8 + wave;       // [0,512)
                int mt0 = (u & 15) * 2;
                int nt0 = ((u >> 4) & 3) * 6;
                int kz8 = u >> 6;
                f32x4 acc[2][6] = {};
                for (int ki = 0; ki < 15; ++ki) {
                    int kt = kz8 * 15 + ki;
                    bf16x8 a[2], b[6];
                    #pragma unroll
                    for (int mi = 0; mi < 2; ++mi)
                        a[mi] = *(const bf16x8*)(apk + ((size_t)(mt0 + mi) * KTC + kt) * 512 + lane * 8);
                    #pragma unroll
                    for (int ni = 0; ni < 6; ++ni)
                        b[ni] = *(const bf16x8*)(cpk + ((size_t)(nt0 + ni) * KTC + kt) * 512 + lane * 8);
                    #pragma unroll
                    for (int mi = 0; mi < 2; ++mi)
                    #pragma unroll
                    for (int ni = 0; ni < 6; ++ni)
                        acc[mi][ni] = MFMA(a[mi], b[ni], acc[mi][ni]);
                }
                float* dst = cp + (size_t)kz8 * Bsz * Hsz;
                #pragma unroll
                for (int mi = 0; mi < 2; ++mi)
                #pragma unroll
                for (int ni = 0; ni < 6; ++ni) {
                    int col = (nt0 + ni) * 16 + l15;
                    #pragma unroll
                    for (int j = 0; j < 4; ++j) {
                        int row = (mt0 + mi) * 16 + lk * 4 + j;
                        dst[(size_t)row * Hsz + col] = acc[mi][ni][j];
                    }
                }
            }
        } else if (blk < 180) {              // THEME(t-1) MLP (split-bf16)
            int tb = blk - 176;
            if (t >= 1) {
                // stage 1: th1 = relu(thm @ sW^T + sb), 128 rows per block
                f32x4 a1[4] = {};
                for (int kt = 0; kt < KTH; ++kt) {
                    size_t ab = ((size_t)((tb * 8 + wave) * KTH + kt) * 2) * 512 + lane * 8;
                    bf16x8 ah = *(const bf16x8*)(tpk + ab);
                    bf16x8 al = *(const bf16x8*)(tpk + ab + 512);
                    #pragma unroll
                    for (int nt = 0; nt < 4; ++nt) {
                        size_t bb2 = ((size_t)(nt * KTH + kt) * 2) * 512 + lane * 8;
                        bf16x8 bh = *(const bf16x8*)(spk + bb2);
                        bf16x8 bl = *(const bf16x8*)(spk + bb2 + 512);
                        a1[nt] = MFMA(ah, bh, a1[nt]);
                        a1[nt] = MFMA(ah, bl, a1[nt]);
                        a1[nt] = MFMA(al, bh, a1[nt]);
                    }
                }
                #pragma unroll
                for (int nt = 0; nt < 4; ++nt) {
                    int col = nt * 16 + l15;
                    #pragma unroll
                    for (int j = 0; j < 4; ++j)
                        th1s[wave * 16 + lk * 4 + j][col] = fmaxf(a1[nt][j] + sb[col], 0.f);
                }
            }
            __syncthreads();
            if (t >= 1) {
                // stage 2: theme = sigmoid(th1 @ rsW^T + rsb)
                int rowl = wave * 16 + l15;
                bf16x8 ah2[2], al2[2];
                #pragma unroll
                for (int kt = 0; kt < 2; ++kt) {
                    bf16x8 zh, zl;
                    #pragma unroll
                    for (int e = 0; e < 8; ++e) {
                        float v = th1s[rowl][kt * 32 + lk * 8 + e];
                        u16 hi = f2bf(v);
                        zh[e] = (short)hi;
                        zl[e] = (short)f2bf(v - bf2f(hi));
                    }
                    ah2[kt] = zh; al2[kt] = zl;
                }
                for (int nt = 0; nt < 24; ++nt) {
                    f32x4 a2 = {};
                    #pragma unroll
                    for (int kt = 0; kt < 2; ++kt) {
                        size_t bb2 = ((size_t)(nt * 2 + kt) * 2) * 512 + lane * 8;
                        bf16x8 bh = *(const bf16x8*)(rpk + bb2);
                        bf16x8 bl = *(const bf16x8*)(rpk + bb2 + 512);
                        a2 = MFMA(ah2[kt], bh, a2);
                        a2 = MFMA(ah2[kt], bl, a2);
                        a2 = MFMA(al2[kt], bh, a2);
                    }
                    int col = nt * 16 + l15;
                    #pragma unroll
                    for (int j = 0; j < 4; ++j) {
                        int rr = tb * 128 + wave * 16 + lk * 4 + j;
                        tho[(size_t)rr * Hsz + col] = sigm(a2[j] + rsb[col]);
                    }
                }
            }
            __syncthreads();
        }
        grid.sync();

        // ================= phase 2: cell (2 rows per block) =================
        for (int r = 0; r < 2; ++r) {
            int b = blk * 2 + r;
            // epilogue for step t-1 (reads tho/cp/hf before overwrite)
            if (t > 0 && tid < Hsz) {
                float convv = cb[tid];
                #pragma unroll
                for (int z = 0; z < 8; ++z)
                    convv += cp[((size_t)z * Bsz + b) * Hsz + tid];
                float val = tho[(size_t)b * Hsz + tid] * convv + hf[(size_t)b * Hsz + tid];
                out_seq[((size_t)b * Tsz + (t - 1)) * Hsz + tid] = val;
                if (t == Tsz) out_last[(size_t)b * Hsz + tid] = val;
            }
            if (t == Tsz) continue;

            float tv = tme[b * Tsz + t];
            const float* xa = xwp + (size_t)((t & 1) * 2) * BG + (size_t)b * Gp;
            const float* xb = xa + BG;
            const float* ha = hwp + (size_t)b * Gp;
            const float* hb = ha + BG;

            if (tid == 0) {
                float zf[6];
                #pragma unroll
                for (int g = 0; g < 6; ++g)
                    zf[g] = xa[g] + xb[g] + ha[g] + hb[g] + bc[g] + tv * wt[g];
                float m = fmaxf(zf[0], fmaxf(zf[1], zf[2]));
                float e0 = expf(zf[0] - m), e1 = expf(zf[1] - m), e2 = expf(zf[2] - m);
                float inv = 1.f / (e0 + e1 + e2);
                float p0 = e0 * inv, p1 = e1 * inv;
                s_fm[0] = p0; s_fm[1] = p0 + p1; s_fm[2] = 1.f;
                float mw = fmaxf(zf[3], fmaxf(zf[4], zf[5]));
                float f0 = expf(zf[3] - mw), f1 = expf(zf[4] - mw), f2 = expf(zf[5] - mw);
                float invw = 1.f / (f0 + f1 + f2);
                float q1 = f1 * invw, q2 = f2 * invw;
                s_im[0] = 1.f; s_im[1] = q1 + q2; s_im[2] = q2;
                float cd = 1.f - (s_fm[0] + s_fm[1] + s_fm[2]) * (1.f / 3.f);
                s_cd = cd;
                bufd[(t % CSs) * Bsz + b] = cd;
                out_dist[(size_t)t * Bsz + b] = cd;
            }
            __syncthreads();

            int mt = b >> 4, l15b = b & 15;
            if (tid < Hsz) {
                int l = tid >> 7;
                float fm = s_fm[l], im = s_im[l];
                int g0 = 6 + tid, g1 = g0 + Hsz, g2 = g0 + 2 * Hsz, g3 = g0 + 3 * Hsz;
                float fg = sigm(xa[g0] + xb[g0] + ha[g0] + hb[g0] + bc[g0] + tv * wt[g0]);
                float ig = sigm(xa[g1] + xb[g1] + ha[g1] + hb[g1] + bc[g1] + tv * wt[g1]);
                float og = sigm(xa[g2] + xb[g2] + ha[g2] + hb[g2] + bc[g2] + tv * wt[g2]);
                float ci = tanhf(xa[g3] + xb[g3] + ha[g3] + hb[g3] + bc[g3] + tv * wt[g3]);
                float cl = cf[(size_t)b * Hsz + tid];
                float ov = fm * im;
                float cn = ov * (fg * cl + ig * ci) + (fm - ov) * cl + (im - ov) * ci;
                float hn = og * tanhf(cn);
                cf[(size_t)b * Hsz + tid] = cn;
                hf[(size_t)b * Hsz + tid] = hn;
                u16 hh = f2bf(hn);
                u16 hl = f2bf(hn - bf2f(hh));
                int pos = (l15b | (((tid >> 3) & 3) << 4)) * 8 + (tid & 7);
                size_t fo = ((size_t)(mt * KTH + (tid >> 5)) * 2) * 512;
                hpk[fo + pos] = hh;
                hpk[fo + 512 + pos] = hl;
                s_hn[tid] = hn;
                bufh[((size_t)(t % CSs) * Bsz + b) * Hsz + tid] = hh;
            }
            __syncthreads();

            if (tid == 0) {
                float vals[CSs];
                float cum = 0.f;
                #pragma unroll
                for (int j = 0; j < CSs; ++j) {
                    int slot = (t + 1 + j) % CSs;
                    float d = (j == CSs - 1) ? s_cd : bufd[slot * Bsz + b];
                    cum += d;
                    vals[j] = cum;
                }
                float mx = vals[0];
                #pragma unroll
                for (int j = 1; j < CSs; ++j) mx = fmaxf(mx, vals[j]);
                float sum = 0.f;
                #pragma unroll
                for (int j = 0; j < CSs; ++j) { vals[j] = expf(vals[j] - mx); sum += vals[j]; }
                float invs = 1.f / sum;
                #pragma unroll
                for (int j = 0; j < CSs; ++j) s_ld[j] = vals[j] * invs;
            }
            __syncthreads();

            if (tid < Hsz) {
                float acc = 0.f;
                #pragma unroll
                for (int j = 0; j < CSs; ++j) {
                    int slot = (t + 1 + j) % CSs;
                    float v = (j == CSs - 1) ? s_hn[tid]
                                             : bf2f(bufh[((size_t)slot * Bsz + b) * Hsz + tid]);
                    float av = v * s_ld[j];
                    int k = tid * CSs + j;
                    int pos = (l15b | (((k >> 3) & 3) << 4)) * 8 + (k & 7);
                    apk[((size_t)(mt * KTC + (k >> 5))) * 512 + pos] = f2bf(av);
                    acc += av;
                }
                float thm = acc * 0.1f;
                u16 th = f2bf(thm);
                u16 tl = f2bf(thm - bf2f(th));
                int pos = (l15b | (((tid >> 3) & 3) << 4)) * 8 + (tid & 7);
                size_t fo = ((size_t)(mt * KTH + (tid >> 5)) * 2) * 512;
                tpk[fo + pos] = th;
                tpk[fo + 512 + pos] = tl;
            }
            __syncthreads();
        }
        if (t < Tsz) grid.sync();
    }
}

extern "C" void kernel_launch(void* const* d_in, const int* in_sizes, int n_in,
                              void* d_out, int out_size, void* d_ws, size_t ws_size,
                              hipStream_t stream) {
    const float* x   = (const float*)d_in[0];
    const float* tme = (const float*)d_in[1];
    const float* kW  = (const float*)d_in[2];
    const float* kb  = (const float*)d_in[3];
    const float* rW  = (const float*)d_in[4];
    const float* rb  = (const float*)d_in[5];
    const float* sW  = (const float*)d_in[6];
    const float* sb  = (const float*)d_in[7];
    const float* rsW = (const float*)d_in[8];
    const float* rsb = (const float*)d_in[9];
    const float* cW  = (const float*)d_in[10];
    const float* cb  = (const float*)d_in[11];

    char* wsb = (char*)d_ws;
    float* outp = (float*)d_out;

    u16* wpk  = (u16*)(wsb + O_WPK);
    u16* xwpk = (u16*)(wsb + O_XWPK);
    u16* cpk  = (u16*)(wsb + O_CPK);
    u16* spk  = (u16*)(wsb + O_SPK);
    u16* rpk  = (u16*)(wsb + O_RPK);
    float* bc = (float*)(wsb + O_BC);
    float* wt = (float*)(wsb + O_WT);
    u16* xpk  = (u16*)(wsb + O_XPK);

    zero4<<<(int)(ZERO_END / 16 + 255) / 256, 256, 0, stream>>>((float4*)wsb, (int)(ZERO_END / 16));
    {
        int nW = Gp * 384 + Gp * 256 + 64 * 384 + 384 * 64 + Gsz;
        build_w<<<(nW + 255) / 256, 256, 0, stream>>>(kW, kb, rW, rb, sW, rsW,
                                                      wpk, xwpk, spk, rpk, bc, wt);
    }
    pack_x<<<(Tsz * Bsz * Dsz) / 256, 256, 0, stream>>>(x, xpk);
    pack_cw<<<(Hsz * Hsz * CSs + 255) / 256, 256, 0, stream>>>(cW, cpk);

    void* args[] = { (void*)&tme, (void*)&sb, (void*)&rsb, (void*)&cb,
                     (void*)&wsb, (void*)&outp };
    hipLaunchCooperativeKernel((void*)persist, dim3(256), dim3(512), args, 0, stream);
}

// Round 7
// 17729.187 us; speedup vs baseline: 1.1226x; 1.1226x over previous
//
#include <hip/hip_runtime.h>
#include <math.h>

typedef unsigned short u16;
typedef __attribute__((ext_vector_type(8))) short bf16x8;
typedef __attribute__((ext_vector_type(4))) float f32x4;

#define MFMA(a, b, c) __builtin_amdgcn_mfma_f32_16x16x32_bf16(a, b, c, 0, 0, 0)

#define Bsz 512
#define Tsz 128
#define Dsz 256
#define Lsz 3
#define CSs 10
#define Hsz 384
#define Gsz 1542
#define HSz 64
#define Gp  1568
#define BG  (Bsz * Gp)
#define KTH 12
#define KTX 8
#define KTC 120
#define NBLK 256

// ---------------- ws layout (byte offsets) ----------------
constexpr size_t SZ_HPK = 32ull * 12 * 2 * 1024;               // 786432
constexpr size_t O_HPK  = 0;                                   // h packed hi/lo
constexpr size_t O_TPK  = O_HPK + SZ_HPK;                      // thm packed hi/lo
constexpr size_t O_CF   = O_TPK + SZ_HPK;                      // f32 B*H
constexpr size_t O_BUFH = O_CF + 786432;                       // u16 10*B*H
constexpr size_t O_BUFD = O_BUFH + 3932160;                    // f32 10*B
constexpr size_t O_BAR  = O_BUFD + 20480;                      // barrier counter (zeroed)
constexpr size_t ZERO_END = O_BAR + 256;
constexpr size_t O_WPK  = ZERO_END;                            // 98*12*2*1024
constexpr size_t O_XWPK = O_WPK + 2408448;                     // 98*8*2*1024
constexpr size_t O_CPK  = O_XWPK + 1605632;                    // 24*120*1024
constexpr size_t O_SPK  = O_CPK + 2949120;                     // 4*12*2*1024
constexpr size_t O_RPK  = O_SPK + 98304;                       // 24*2*2*1024
constexpr size_t O_BC   = O_RPK + 98304;                       // f32 1568
constexpr size_t O_WT   = O_BC + 6272;
constexpr size_t O_XWP  = O_WT + 6272;                         // f32 4*B*Gp (2 buf x 2 kz)
constexpr size_t O_HWP  = O_XWP + 4ull * BG * 4;               // f32 2*B*Gp (2 kz)
constexpr size_t O_CP   = O_HWP + 2ull * BG * 4;               // f32 8*B*H
constexpr size_t O_APK  = O_CP + 8ull * Bsz * Hsz * 4;         // u16 32*120*1024B
constexpr size_t O_THO  = O_APK + 3932160;                     // f32 B*H (theme out)
constexpr size_t O_HF   = O_THO + 786432;                      // f32 B*H
constexpr size_t O_XPK  = O_HF + 786432;                       // u16 128*512KB = 67MB

__device__ __forceinline__ u16 f2bf(float f) {
    unsigned u = __float_as_uint(f);
    unsigned r = (u + 0x7FFFu + ((u >> 16) & 1u)) >> 16;
    return (u16)r;
}
__device__ __forceinline__ float bf2f(u16 v) {
    return __uint_as_float(((unsigned)v) << 16);
}
__device__ __forceinline__ float sigm(float v) { return 1.f / (1.f + expf(-v)); }

// agent-scope grid barrier: release-arrive on a monotone counter, relaxed poll,
// single acquire fence after. Coherence point = L3 (NOT system/HBM like
// cg::grid.sync) — cross-phase data stays in Infinity Cache.
__device__ __forceinline__ void gbar(unsigned* cnt, unsigned target) {
    __syncthreads();
    if (threadIdx.x == 0) {
        __hip_atomic_fetch_add(cnt, 1u, __ATOMIC_RELEASE, __HIP_MEMORY_SCOPE_AGENT);
        while (__hip_atomic_load(cnt, __ATOMIC_RELAXED, __HIP_MEMORY_SCOPE_AGENT) < target) {
            __builtin_amdgcn_s_sleep(2);
        }
        __builtin_amdgcn_fence(__ATOMIC_ACQUIRE, "agent");
    }
    __syncthreads();
}

__global__ __launch_bounds__(256) void zero4(float4* __restrict__ p, int n4) {
    int i = blockIdx.x * 256 + threadIdx.x;
    if (i < n4) p[i] = make_float4(0.f, 0.f, 0.f, 0.f);
}

__global__ __launch_bounds__(256) void build_w(const float* __restrict__ kW,
                                               const float* __restrict__ kb,
                                               const float* __restrict__ rW,
                                               const float* __restrict__ rb,
                                               const float* __restrict__ sW,
                                               const float* __restrict__ rsW,
                                               u16* __restrict__ wpk,
                                               u16* __restrict__ xwpk,
                                               u16* __restrict__ spk,
                                               u16* __restrict__ rpk,
                                               float* __restrict__ bc,
                                               float* __restrict__ wt) {
    const int N1 = Gp * 384, N2 = Gp * 256, N3 = 64 * 384, N4 = 384 * 64;
    int idx = blockIdx.x * 256 + threadIdx.x;
    if (idx < N1) {
        int g = idx / 384, k = idx % 384;
        float v = (g < Gsz) ? rW[g * (Hsz + 1) + k] : 0.f;
        u16 hi = f2bf(v), lo = f2bf(v - bf2f(hi));
        size_t fo = ((size_t)((g >> 4) * KTH + (k >> 5)) * 2) * 512;
        int pos = ((g & 15) | (((k >> 3) & 3) << 4)) * 8 + (k & 7);
        wpk[fo + pos] = hi; wpk[fo + 512 + pos] = lo;
    } else if (idx < N1 + N2) {
        int i = idx - N1;
        int g = i / 256, k = i % 256;
        float v = (g < Gsz) ? kW[g * (Dsz + 1) + k] : 0.f;
        u16 hi = f2bf(v), lo = f2bf(v - bf2f(hi));
        size_t fo = ((size_t)((g >> 4) * KTX + (k >> 5)) * 2) * 512;
        int pos = ((g & 15) | (((k >> 3) & 3) << 4)) * 8 + (k & 7);
        xwpk[fo + pos] = hi; xwpk[fo + 512 + pos] = lo;
    } else if (idx < N1 + N2 + N3) {
        int i = idx - N1 - N2;
        int g = i / 384, k = i % 384;              // g<64
        float v = sW[g * Hsz + k];
        u16 hi = f2bf(v), lo = f2bf(v - bf2f(hi));
        size_t fo = ((size_t)((g >> 4) * KTH + (k >> 5)) * 2) * 512;
        int pos = ((g & 15) | (((k >> 3) & 3) << 4)) * 8 + (k & 7);
        spk[fo + pos] = hi; spk[fo + 512 + pos] = lo;
    } else if (idx < N1 + N2 + N3 + N4) {
        int i = idx - N1 - N2 - N3;
        int g = i / 64, k = i % 64;                // g<384
        float v = rsW[g * HSz + k];
        u16 hi = f2bf(v), lo = f2bf(v - bf2f(hi));
        size_t fo = ((size_t)((g >> 4) * 2 + (k >> 5)) * 2) * 512;
        int pos = ((g & 15) | (((k >> 3) & 3) << 4)) * 8 + (k & 7);
        rpk[fo + pos] = hi; rpk[fo + 512 + pos] = lo;
    } else if (idx < N1 + N2 + N3 + N4 + Gsz) {
        int g = idx - N1 - N2 - N3 - N4;
        bc[g] = kb[g] + rb[g];
        wt[g] = kW[g * (Dsz + 1) + Dsz] + rW[g * (Hsz + 1) + Hsz];
    }
}

__global__ __launch_bounds__(256) void pack_x(const float* __restrict__ x,
                                              u16* __restrict__ xpk) {
    int idx = blockIdx.x * 256 + threadIdx.x;
    int k = idx & 255, b = (idx >> 8) & 511, t = idx >> 17;
    float v = x[((size_t)b * Tsz + t) * Dsz + k];
    u16 hi = f2bf(v), lo = f2bf(v - bf2f(hi));
    size_t fo = (((size_t)t * 32 + (b >> 4)) * KTX + (k >> 5)) * 2 * 512;
    int pos = ((b & 15) | (((k >> 3) & 3) << 4)) * 8 + (k & 7);
    xpk[fo + pos] = hi;
    xpk[fo + 512 + pos] = lo;
}

__global__ __launch_bounds__(256) void pack_cw(const float* __restrict__ cW,
                                               u16* __restrict__ cpk) {
    int idx = blockIdx.x * 256 + threadIdx.x;
    if (idx >= Hsz * Hsz * CSs) return;
    int o = idx / (Hsz * CSs), k = idx % (Hsz * CSs);
    size_t fo = ((size_t)(o >> 4) * KTC + (k >> 5)) * 512;
    int pos = ((o & 15) | (((k >> 3) & 3) << 4)) * 8 + (k & 7);
    cpk[fo + pos] = f2bf(cW[idx]);
}

// split-bf16 GEMM slab: 32 rows x 112 cols per wave, kt in [k0,k1)
__device__ __forceinline__ void gemm_hx(const u16* __restrict__ A,
                                        const u16* __restrict__ B,
                                        int nkt, int k0, int k1,
                                        int mt0, int nt0, float* __restrict__ dst,
                                        int lane, int l15, int lk) {
    f32x4 acc[2][7] = {};
    for (int kt = k0; kt < k1; ++kt) {
        bf16x8 ah[2], al[2];
        #pragma unroll
        for (int mi = 0; mi < 2; ++mi) {
            size_t fb = ((size_t)((mt0 + mi) * nkt + kt) * 2) * 512 + lane * 8;
            ah[mi] = *(const bf16x8*)(A + fb);
            al[mi] = *(const bf16x8*)(A + fb + 512);
        }
        #pragma unroll
        for (int ni = 0; ni < 7; ++ni) {
            size_t fb = ((size_t)((nt0 + ni) * nkt + kt) * 2) * 512 + lane * 8;
            bf16x8 bh = *(const bf16x8*)(B + fb);
            bf16x8 bl = *(const bf16x8*)(B + fb + 512);
            #pragma unroll
            for (int mi = 0; mi < 2; ++mi) {
                acc[mi][ni] = MFMA(ah[mi], bh, acc[mi][ni]);
                acc[mi][ni] = MFMA(ah[mi], bl, acc[mi][ni]);
                acc[mi][ni] = MFMA(al[mi], bh, acc[mi][ni]);
            }
        }
    }
    #pragma unroll
    for (int mi = 0; mi < 2; ++mi)
    #pragma unroll
    for (int ni = 0; ni < 7; ++ni) {
        int col = (nt0 + ni) * 16 + l15;
        #pragma unroll
        for (int j = 0; j < 4; ++j) {
            int row = (mt0 + mi) * 16 + lk * 4 + j;
            dst[(size_t)row * Gp + col] = acc[mi][ni][j];
        }
    }
}

__global__ __launch_bounds__(512, 2) void persist(const float* __restrict__ tme,
                                                  const float* __restrict__ sb,
                                                  const float* __restrict__ rsb,
                                                  const float* __restrict__ cb,
                                                  char* __restrict__ ws,
                                                  float* __restrict__ out) {
    u16*   hpk  = (u16*)(ws + O_HPK);
    u16*   tpk  = (u16*)(ws + O_TPK);
    float* cf   = (float*)(ws + O_CF);
    u16*   bufh = (u16*)(ws + O_BUFH);
    float* bufd = (float*)(ws + O_BUFD);
    unsigned* bar = (unsigned*)(ws + O_BAR);
    const u16* wpk  = (const u16*)(ws + O_WPK);
    const u16* xwpk = (const u16*)(ws + O_XWPK);
    const u16* cpk  = (const u16*)(ws + O_CPK);
    const u16* spk  = (const u16*)(ws + O_SPK);
    const u16* rpk  = (const u16*)(ws + O_RPK);
    const float* bc = (const float*)(ws + O_BC);
    const float* wt = (const float*)(ws + O_WT);
    float* xwp = (float*)(ws + O_XWP);
    float* hwp = (float*)(ws + O_HWP);
    float* cp  = (float*)(ws + O_CP);
    u16*   apk = (u16*)(ws + O_APK);
    float* tho = (float*)(ws + O_THO);
    float* hf  = (float*)(ws + O_HF);
    const u16* xpk = (const u16*)(ws + O_XPK);

    float* out_last = out;
    float* out_seq  = out + (size_t)Bsz * Hsz;
    float* out_dist = out_seq + (size_t)Bsz * Tsz * Hsz;

    int blk = blockIdx.x, tid = threadIdx.x;
    int wave = tid >> 6, lane = tid & 63, l15 = lane & 15, lk = lane >> 4;
    unsigned ep = 0;

    __shared__ float th1s[128][65];
    __shared__ float s_hn[Hsz];
    __shared__ float s_ld[CSs];
    __shared__ float s_fm[4], s_im[4];
    __shared__ float s_cd;

    for (int t = 0; t <= Tsz; ++t) {
        // ================= phase 1: GEMMs =================
        if (blk < 56) {                      // HW(t) = h(t-1) @ rW^T, kz-split
            if (t < Tsz) {
                int kz = blk & 1, sub = blk >> 1;
                int u = sub * 8 + wave;
                gemm_hx(hpk, wpk, KTH, kz * 6, kz * 6 + 6,
                        (u & 15) * 2, (u >> 4) * 7, hwp + (size_t)kz * BG,
                        lane, l15, lk);
            }
        } else if (blk < 112) {              // XW(t+1) = x(t+1) @ kW^T, kz-split
            if (t + 1 < Tsz) {
                int bb = blk - 56;
                int kz = bb & 1, sub = bb >> 1;
                int u = sub * 8 + wave;
                const u16* xs = xpk + (size_t)(t + 1) * 262144;
                gemm_hx(xs, xwpk, KTX, kz * 4, kz * 4 + 4,
                        (u & 15) * 2, (u >> 4) * 7,
                        xwp + (size_t)(((t + 1) & 1) * 2 + kz) * BG,
                        lane, l15, lk);
            }
        } else if (blk < 176) {              // CONV(t-1)  (t==0: bootstrap XW(0))
            if (t == 0) {
                if (blk < 168) {
                    int bb = blk - 112;
                    int kz = bb & 1, sub = bb >> 1;
                    int u = sub * 8 + wave;
                    gemm_hx(xpk, xwpk, KTX, kz * 4, kz * 4 + 4,
                            (u & 15) * 2, (u >> 4) * 7, xwp + (size_t)kz * BG,
                            lane, l15, lk);
                }
            } else {
                int u = (blk - 112) * 8 + wave;       // [0,512)
                int mt0 = (u & 15) * 2;
                int nt0 = ((u >> 4) & 3) * 6;
                int kz8 = u >> 6;
                f32x4 acc[2][6] = {};
                for (int ki = 0; ki < 15; ++ki) {
                    int kt = kz8 * 15 + ki;
                    bf16x8 a[2], b[6];
                    #pragma unroll
                    for (int mi = 0; mi < 2; ++mi)
                        a[mi] = *(const bf16x8*)(apk + ((size_t)(mt0 + mi) * KTC + kt) * 512 + lane * 8);
                    #pragma unroll
                    for (int ni = 0; ni < 6; ++ni)
                        b[ni] = *(const bf16x8*)(cpk + ((size_t)(nt0 + ni) * KTC + kt) * 512 + lane * 8);
                    #pragma unroll
                    for (int mi = 0; mi < 2; ++mi)
                    #pragma unroll
                    for (int ni = 0; ni < 6; ++ni)
                        acc[mi][ni] = MFMA(a[mi], b[ni], acc[mi][ni]);
                }
                float* dst = cp + (size_t)kz8 * Bsz * Hsz;
                #pragma unroll
                for (int mi = 0; mi < 2; ++mi)
                #pragma unroll
                for (int ni = 0; ni < 6; ++ni) {
                    int col = (nt0 + ni) * 16 + l15;
                    #pragma unroll
                    for (int j = 0; j < 4; ++j) {
                        int row = (mt0 + mi) * 16 + lk * 4 + j;
                        dst[(size_t)row * Hsz + col] = acc[mi][ni][j];
                    }
                }
            }
        } else if (blk < 180) {              // THEME(t-1) MLP (split-bf16)
            int tb = blk - 176;
            if (t >= 1) {
                f32x4 a1[4] = {};
                for (int kt = 0; kt < KTH; ++kt) {
                    size_t ab = ((size_t)((tb * 8 + wave) * KTH + kt) * 2) * 512 + lane * 8;
                    bf16x8 ah = *(const bf16x8*)(tpk + ab);
                    bf16x8 al = *(const bf16x8*)(tpk + ab + 512);
                    #pragma unroll
                    for (int nt = 0; nt < 4; ++nt) {
                        size_t bb2 = ((size_t)(nt * KTH + kt) * 2) * 512 + lane * 8;
                        bf16x8 bh = *(const bf16x8*)(spk + bb2);
                        bf16x8 bl = *(const bf16x8*)(spk + bb2 + 512);
                        a1[nt] = MFMA(ah, bh, a1[nt]);
                        a1[nt] = MFMA(ah, bl, a1[nt]);
                        a1[nt] = MFMA(al, bh, a1[nt]);
                    }
                }
                #pragma unroll
                for (int nt = 0; nt < 4; ++nt) {
                    int col = nt * 16 + l15;
                    #pragma unroll
                    for (int j = 0; j < 4; ++j)
                        th1s[wave * 16 + lk * 4 + j][col] = fmaxf(a1[nt][j] + sb[col], 0.f);
                }
            }
            __syncthreads();
            if (t >= 1) {
                int rowl = wave * 16 + l15;
                bf16x8 ah2[2], al2[2];
                #pragma unroll
                for (int kt = 0; kt < 2; ++kt) {
                    bf16x8 zh, zl;
                    #pragma unroll
                    for (int e = 0; e < 8; ++e) {
                        float v = th1s[rowl][kt * 32 + lk * 8 + e];
                        u16 hi = f2bf(v);
                        zh[e] = (short)hi;
                        zl[e] = (short)f2bf(v - bf2f(hi));
                    }
                    ah2[kt] = zh; al2[kt] = zl;
                }
                for (int nt = 0; nt < 24; ++nt) {
                    f32x4 a2 = {};
                    #pragma unroll
                    for (int kt = 0; kt < 2; ++kt) {
                        size_t bb2 = ((size_t)(nt * 2 + kt) * 2) * 512 + lane * 8;
                        bf16x8 bh = *(const bf16x8*)(rpk + bb2);
                        bf16x8 bl = *(const bf16x8*)(rpk + bb2 + 512);
                        a2 = MFMA(ah2[kt], bh, a2);
                        a2 = MFMA(ah2[kt], bl, a2);
                        a2 = MFMA(al2[kt], bh, a2);
                    }
                    int col = nt * 16 + l15;
                    #pragma unroll
                    for (int j = 0; j < 4; ++j) {
                        int rr = tb * 128 + wave * 16 + lk * 4 + j;
                        tho[(size_t)rr * Hsz + col] = sigm(a2[j] + rsb[col]);
                    }
                }
            }
            __syncthreads();
        }
        gbar(bar, (++ep) * NBLK);

        // ================= phase 2: cell (2 rows per block) =================
        for (int r = 0; r < 2; ++r) {
            int b = blk * 2 + r;
            if (t > 0 && tid < Hsz) {
                float convv = cb[tid];
                #pragma unroll
                for (int z = 0; z < 8; ++z)
                    convv += cp[((size_t)z * Bsz + b) * Hsz + tid];
                float val = tho[(size_t)b * Hsz + tid] * convv + hf[(size_t)b * Hsz + tid];
                out_seq[((size_t)b * Tsz + (t - 1)) * Hsz + tid] = val;
                if (t == Tsz) out_last[(size_t)b * Hsz + tid] = val;
            }
            if (t == Tsz) continue;

            float tv = tme[b * Tsz + t];
            const float* xa = xwp + (size_t)((t & 1) * 2) * BG + (size_t)b * Gp;
            const float* xb = xa + BG;
            const float* ha = hwp + (size_t)b * Gp;
            const float* hb = ha + BG;

            if (tid == 0) {
                float zf[6];
                #pragma unroll
                for (int g = 0; g < 6; ++g)
                    zf[g] = xa[g] + xb[g] + ha[g] + hb[g] + bc[g] + tv * wt[g];
                float m = fmaxf(zf[0], fmaxf(zf[1], zf[2]));
                float e0 = expf(zf[0] - m), e1 = expf(zf[1] - m), e2 = expf(zf[2] - m);
                float inv = 1.f / (e0 + e1 + e2);
                float p0 = e0 * inv, p1 = e1 * inv;
                s_fm[0] = p0; s_fm[1] = p0 + p1; s_fm[2] = 1.f;
                float mw = fmaxf(zf[3], fmaxf(zf[4], zf[5]));
                float f0 = expf(zf[3] - mw), f1 = expf(zf[4] - mw), f2 = expf(zf[5] - mw);
                float invw = 1.f / (f0 + f1 + f2);
                float q1 = f1 * invw, q2 = f2 * invw;
                s_im[0] = 1.f; s_im[1] = q1 + q2; s_im[2] = q2;
                float cd = 1.f - (s_fm[0] + s_fm[1] + s_fm[2]) * (1.f / 3.f);
                s_cd = cd;
                bufd[(t % CSs) * Bsz + b] = cd;
                out_dist[(size_t)t * Bsz + b] = cd;
            }
            __syncthreads();

            int mt = b >> 4, l15b = b & 15;
            if (tid < Hsz) {
                int l = tid >> 7;
                float fm = s_fm[l], im = s_im[l];
                int g0 = 6 + tid, g1 = g0 + Hsz, g2 = g0 + 2 * Hsz, g3 = g0 + 3 * Hsz;
                float fg = sigm(xa[g0] + xb[g0] + ha[g0] + hb[g0] + bc[g0] + tv * wt[g0]);
                float ig = sigm(xa[g1] + xb[g1] + ha[g1] + hb[g1] + bc[g1] + tv * wt[g1]);
                float og = sigm(xa[g2] + xb[g2] + ha[g2] + hb[g2] + bc[g2] + tv * wt[g2]);
                float ci = tanhf(xa[g3] + xb[g3] + ha[g3] + hb[g3] + bc[g3] + tv * wt[g3]);
                float cl = cf[(size_t)b * Hsz + tid];
                float ov = fm * im;
                float cn = ov * (fg * cl + ig * ci) + (fm - ov) * cl + (im - ov) * ci;
                float hn = og * tanhf(cn);
                cf[(size_t)b * Hsz + tid] = cn;
                hf[(size_t)b * Hsz + tid] = hn;
                u16 hh = f2bf(hn);
                u16 hl = f2bf(hn - bf2f(hh));
                int pos = (l15b | (((tid >> 3) & 3) << 4)) * 8 + (tid & 7);
                size_t fo = ((size_t)(mt * KTH + (tid >> 5)) * 2) * 512;
                hpk[fo + pos] = hh;
                hpk[fo + 512 + pos] = hl;
                s_hn[tid] = hn;
                bufh[((size_t)(t % CSs) * Bsz + b) * Hsz + tid] = hh;
            }
            __syncthreads();

            if (tid == 0) {
                float vals[CSs];
                float cum = 0.f;
                #pragma unroll
                for (int j = 0; j < CSs; ++j) {
                    int slot = (t + 1 + j) % CSs;
                    float d = (j == CSs - 1) ? s_cd : bufd[slot * Bsz + b];
                    cum += d;
                    vals[j] = cum;
                }
                float mx = vals[0];
                #pragma unroll
                for (int j = 1; j < CSs; ++j) mx = fmaxf(mx, vals[j]);
                float sum = 0.f;
                #pragma unroll
                for (int j = 0; j < CSs; ++j) { vals[j] = expf(vals[j] - mx); sum += vals[j]; }
                float invs = 1.f / sum;
                #pragma unroll
                for (int j = 0; j < CSs; ++j) s_ld[j] = vals[j] * invs;
            }
            __syncthreads();

            if (tid < Hsz) {
                float acc = 0.f;
                #pragma unroll
                for (int j = 0; j < CSs; ++j) {
                    int slot = (t + 1 + j) % CSs;
                    float v = (j == CSs - 1) ? s_hn[tid]
                                             : bf2f(bufh[((size_t)slot * Bsz + b) * Hsz + tid]);
                    float av = v * s_ld[j];
                    int k = tid * CSs + j;
                    int pos = (l15b | (((k >> 3) & 3) << 4)) * 8 + (k & 7);
                    apk[((size_t)(mt * KTC + (k >> 5))) * 512 + pos] = f2bf(av);
                    acc += av;
                }
                float thm = acc * 0.1f;
                u16 th = f2bf(thm);
                u16 tl = f2bf(thm - bf2f(th));
                int pos = (l15b | (((tid >> 3) & 3) << 4)) * 8 + (tid & 7);
                size_t fo = ((size_t)(mt * KTH + (tid >> 5)) * 2) * 512;
                tpk[fo + pos] = th;
                tpk[fo + 512 + pos] = tl;
            }
            __syncthreads();
        }
        if (t < Tsz) gbar(bar, (++ep) * NBLK);
    }
}

extern "C" void kernel_launch(void* const* d_in, const int* in_sizes, int n_in,
                              void* d_out, int out_size, void* d_ws, size_t ws_size,
                              hipStream_t stream) {
    const float* x   = (const float*)d_in[0];
    const float* tme = (const float*)d_in[1];
    const float* kW  = (const float*)d_in[2];
    const float* kb  = (const float*)d_in[3];
    const float* rW  = (const float*)d_in[4];
    const float* rb  = (const float*)d_in[5];
    const float* sW  = (const float*)d_in[6];
    const float* sb  = (const float*)d_in[7];
    const float* rsW = (const float*)d_in[8];
    const float* rsb = (const float*)d_in[9];
    const float* cW  = (const float*)d_in[10];
    const float* cb  = (const float*)d_in[11];

    char* wsb = (char*)d_ws;
    float* outp = (float*)d_out;

    u16* wpk  = (u16*)(wsb + O_WPK);
    u16* xwpk = (u16*)(wsb + O_XWPK);
    u16* cpk  = (u16*)(wsb + O_CPK);
    u16* spk  = (u16*)(wsb + O_SPK);
    u16* rpk  = (u16*)(wsb + O_RPK);
    float* bc = (float*)(wsb + O_BC);
    float* wt = (float*)(wsb + O_WT);
    u16* xpk  = (u16*)(wsb + O_XPK);

    zero4<<<(int)(ZERO_END / 16 + 255) / 256, 256, 0, stream>>>((float4*)wsb, (int)(ZERO_END / 16));
    {
        int nW = Gp * 384 + Gp * 256 + 64 * 384 + 384 * 64 + Gsz;
        build_w<<<(nW + 255) / 256, 256, 0, stream>>>(kW, kb, rW, rb, sW, rsW,
                                                      wpk, xwpk, spk, rpk, bc, wt);
    }
    pack_x<<<(Tsz * Bsz * Dsz) / 256, 256, 0, stream>>>(x, xpk);
    pack_cw<<<(Hsz * Hsz * CSs + 255) / 256, 256, 0, stream>>>(cW, cpk);

    void* args[] = { (void*)&tme, (void*)&sb, (void*)&rsb, (void*)&cb,
                     (void*)&wsb, (void*)&outp };
    hipLaunchCooperativeKernel((void*)persist, dim3(NBLK), dim3(512), args, 0, stream);
}